// Round 6
// baseline (54.610 us; speedup 1.0000x reference)
//
#include <hip/hip_runtime.h>
#include <stdint.h>

// Chamfer L1, B=4, N=M=8192, 3-D points.
// u16 fixed-point quantization (4096/unit, +8 offset):
//   pair distance = 2x v_sad_u16 (half-rate: 4cyc), min via v_min3_u32.
// VALU floor = 8.39M wave-pairs x 9 cyc / 1024 SIMDs = 30.7 us.
// 2048 blocks (8/CU -> 8 waves/SIMD) to saturate VALU; per-chunk mins
// combined via global atomicMin into 256 KB ws, then a tiny sum kernel.

#define BATCH    4
#define NPTS     8192
#define QSCALE   4096.0f
#define QOFFS    8.0f
#define NCHUNK   32
#define CHUNKPTS (NPTS / NCHUNK)   // 256 refs per block
#define THREADS  256
#define QPL      4                 // queries per lane
#define QPB      (THREADS * QPL)   // 1024 queries per block
#define NQG      (NPTS / QPB)      // 8 query groups

static __device__ __forceinline__ uint32_t sad_u16(uint32_t a, uint32_t b, uint32_t c) {
#if __has_builtin(__builtin_amdgcn_sad_u16)
    return __builtin_amdgcn_sad_u16(a, b, c);
#else
    uint32_t d;
    asm("v_sad_u16 %0, %1, %2, %3" : "=v"(d) : "v"(a), "v"(b), "v"(c));
    return d;
#endif
}

static __device__ __forceinline__ uint32_t min3_u32(uint32_t a, uint32_t b, uint32_t c) {
    uint32_t d;
    asm("v_min3_u32 %0, %1, %2, %3" : "=v"(d) : "v"(a), "v"(b), "v"(c));
    return d;
}

static __device__ __forceinline__ uint32_t quant(float x) {
    float v = (x + QOFFS) * QSCALE;
    v = fminf(fmaxf(v, 0.0f), 65535.0f);
    return (uint32_t)(v + 0.5f);
}

__global__ __launch_bounds__(THREADS, 8) void chamfer_partial_kernel(
    const float* __restrict__ pred, const float* __restrict__ target,
    uint32_t* __restrict__ wsmin)
{
    __shared__ __align__(16) uint2 tile[CHUNKPTS];   // 2 KiB

    const int t    = threadIdx.x;
    const int qg   = blockIdx.x >> 5;     // 0..7
    const int c    = blockIdx.x & 31;     // 0..31
    const int dirb = blockIdx.y;          // 0..7
    const int dir  = dirb >> 2;           // 0: pred->target, 1: target->pred
    const int b    = dirb & 3;

    const float* qbase = (dir == 0 ? pred : target) + (size_t)b * NPTS * 3;
    const float* rbase = (dir == 0 ? target : pred) + (size_t)b * NPTS * 3;

    // stage this block's 256-ref chunk, quantized+packed (1 pt/thread)
    {
        const float* rp = rbase + (size_t)(c * CHUNKPTS + t) * 3;
        tile[t] = make_uint2(quant(rp[0]) | (quant(rp[1]) << 16), quant(rp[2]));
    }

    // my 4 queries
    uint32_t qxy[QPL], qz[QPL], best[QPL];
    #pragma unroll
    for (int k = 0; k < QPL; ++k) {
        int q = qg * QPB + k * THREADS + t;
        const float* qp = qbase + (size_t)q * 3;
        qxy[k]  = quant(qp[0]) | (quant(qp[1]) << 16);
        qz[k]   = quant(qp[2]);
        best[k] = 0xFFFFFFFFu;
    }
    __syncthreads();

    // scan: one broadcast ds_read_b128 = 2 points, shared by 4 queries
    const uint4* tp = reinterpret_cast<const uint4*>(tile);
    #pragma unroll 4
    for (int j = 0; j < CHUNKPTS / 2; ++j) {
        uint4 v = tp[j];
        #pragma unroll
        for (int k = 0; k < QPL; ++k) {
            uint32_t d0 = sad_u16(v.y, qz[k], sad_u16(v.x, qxy[k], 0u));
            uint32_t d1 = sad_u16(v.w, qz[k], sad_u16(v.z, qxy[k], 0u));
            best[k] = min3_u32(d0, d1, best[k]);
        }
    }

    // fold this chunk's per-query mins into the global per-query min
    uint32_t* dst = wsmin + (size_t)dirb * NPTS + qg * QPB + t;
    #pragma unroll
    for (int k = 0; k < QPL; ++k)
        atomicMin(&dst[k * THREADS], best[k]);
}

__global__ __launch_bounds__(256) void chamfer_reduce_kernel(
    const uint32_t* __restrict__ wsmin, float* __restrict__ out)
{
    const int tid = blockIdx.x * 256 + threadIdx.x;   // 16384 threads
    uint4 v = reinterpret_cast<const uint4*>(wsmin)[tid];
    float fsum = (float)v.x + (float)v.y + (float)v.z + (float)v.w;
    #pragma unroll
    for (int off = 32; off > 0; off >>= 1)
        fsum += __shfl_down(fsum, off);
    if ((threadIdx.x & 63) == 0)
        atomicAdd(out, fsum * (1.0f / (QSCALE * (float)BATCH)));
}

extern "C" void kernel_launch(void* const* d_in, const int* in_sizes, int n_in,
                              void* d_out, int out_size, void* d_ws, size_t ws_size,
                              hipStream_t stream) {
    const float* pred   = (const float*)d_in[0];
    const float* target = (const float*)d_in[1];
    float* out = (float*)d_out;
    uint32_t* wsmin = (uint32_t*)d_ws;   // 8 dirb x 8192 x u32 = 256 KiB

    hipMemsetAsync(wsmin, 0xFF, (size_t)8 * NPTS * sizeof(uint32_t), stream);
    hipMemsetAsync(out, 0, sizeof(float), stream);

    dim3 grid(NQG * NCHUNK, 2 * BATCH);   // 256 x 8 = 2048 blocks, 8/CU
    chamfer_partial_kernel<<<grid, THREADS, 0, stream>>>(pred, target, wsmin);
    chamfer_reduce_kernel<<<64, 256, 0, stream>>>(wsmin, out);
}

// Round 7
// 53.526 us; speedup vs baseline: 1.0203x; 1.0203x over previous
//
#include <hip/hip_runtime.h>
#include <stdint.h>

// Chamfer L1, B=4, N=M=8192, 3-D points.
// u16 fixed-point quantization (4096/unit, +8 offset):
//   pair distance = 2x v_sad_u16 (half-rate: 4 cyc), min via v_min3_u32.
// VALU floor = 8.39M wave-pairs x 9 cyc / 1024 SIMDs = 30.7 us.
// QPL=8: one ds_read_b128 broadcast (2 pts) feeds 8 queries = 16 pairs,
// LDS issue ~16k cyc/CU << 74k VALU cyc/CU. 2048 blocks = 8/CU = 8 waves/SIMD.
// Per-chunk mins folded via global atomicMin (256 KB ws); 1-block reduce
// writes out directly (no out-memset).

#define BATCH    4
#define NPTS     8192
#define QSCALE   4096.0f
#define QOFFS    8.0f
#define NCHUNK   64
#define CHUNKPTS (NPTS / NCHUNK)   // 128 refs per block
#define THREADS  256
#define QPL      8                 // queries per lane
#define QPB      (THREADS * QPL)   // 2048 queries per block
#define NQG      (NPTS / QPB)      // 4 query groups

static __device__ __forceinline__ uint32_t sad_u16(uint32_t a, uint32_t b, uint32_t c) {
#if __has_builtin(__builtin_amdgcn_sad_u16)
    return __builtin_amdgcn_sad_u16(a, b, c);
#else
    uint32_t d;
    asm("v_sad_u16 %0, %1, %2, %3" : "=v"(d) : "v"(a), "v"(b), "v"(c));
    return d;
#endif
}

static __device__ __forceinline__ uint32_t min3_u32(uint32_t a, uint32_t b, uint32_t c) {
    uint32_t d;
    asm("v_min3_u32 %0, %1, %2, %3" : "=v"(d) : "v"(a), "v"(b), "v"(c));
    return d;
}

static __device__ __forceinline__ uint32_t quant(float x) {
    float v = (x + QOFFS) * QSCALE;
    v = fminf(fmaxf(v, 0.0f), 65535.0f);
    return (uint32_t)(v + 0.5f);
}

__global__ __launch_bounds__(THREADS, 8) void chamfer_partial_kernel(
    const float* __restrict__ pred, const float* __restrict__ target,
    uint32_t* __restrict__ wsmin)
{
    __shared__ __align__(16) uint2 tile[CHUNKPTS];   // 1 KiB

    const int t    = threadIdx.x;
    const int qg   = blockIdx.x >> 6;     // 0..3
    const int c    = blockIdx.x & 63;     // 0..63
    const int dirb = blockIdx.y;          // 0..7
    const int dir  = dirb >> 2;           // 0: pred->target, 1: target->pred
    const int b    = dirb & 3;

    const float* qbase = (dir == 0 ? pred : target) + (size_t)b * NPTS * 3;
    const float* rbase = (dir == 0 ? target : pred) + (size_t)b * NPTS * 3;

    // stage this block's 128-ref chunk, quantized+packed
    if (t < CHUNKPTS) {
        const float* rp = rbase + (size_t)(c * CHUNKPTS + t) * 3;
        tile[t] = make_uint2(quant(rp[0]) | (quant(rp[1]) << 16), quant(rp[2]));
    }

    // my 8 queries
    uint32_t qxy[QPL], qz[QPL], best[QPL];
    #pragma unroll
    for (int k = 0; k < QPL; ++k) {
        int q = qg * QPB + k * THREADS + t;
        const float* qp = qbase + (size_t)q * 3;
        qxy[k]  = quant(qp[0]) | (quant(qp[1]) << 16);
        qz[k]   = quant(qp[2]);
        best[k] = 0xFFFFFFFFu;
    }
    __syncthreads();

    // scan: one broadcast ds_read_b128 = 2 points, shared by 8 queries
    const uint4* tp = reinterpret_cast<const uint4*>(tile);
    #pragma unroll 2
    for (int j = 0; j < CHUNKPTS / 2; ++j) {
        uint4 v = tp[j];
        #pragma unroll
        for (int k = 0; k < QPL; ++k) {
            uint32_t d0 = sad_u16(v.y, qz[k], sad_u16(v.x, qxy[k], 0u));
            uint32_t d1 = sad_u16(v.w, qz[k], sad_u16(v.z, qxy[k], 0u));
            best[k] = min3_u32(d0, d1, best[k]);
        }
    }

    // fold this chunk's per-query mins into the global per-query min
    uint32_t* dst = wsmin + (size_t)dirb * NPTS + qg * QPB + t;
    #pragma unroll
    for (int k = 0; k < QPL; ++k)
        atomicMin(&dst[k * THREADS], best[k]);
}

__global__ __launch_bounds__(1024) void chamfer_reduce_kernel(
    const uint32_t* __restrict__ wsmin, float* __restrict__ out)
{
    __shared__ float ssum[16];
    const int t = threadIdx.x;
    const uint4* p = reinterpret_cast<const uint4*>(wsmin);   // 16384 uint4
    float s = 0.0f;
    #pragma unroll
    for (int i = 0; i < 16; ++i) {
        uint4 v = p[t + i * 1024];
        s += (float)v.x + (float)v.y + (float)v.z + (float)v.w;
    }
    #pragma unroll
    for (int off = 32; off > 0; off >>= 1)
        s += __shfl_down(s, off);
    if ((t & 63) == 0) ssum[t >> 6] = s;
    __syncthreads();
    if (t == 0) {
        float tot = 0.0f;
        #pragma unroll
        for (int w = 0; w < 16; ++w) tot += ssum[w];
        out[0] = tot * (1.0f / (QSCALE * (float)BATCH));
    }
}

extern "C" void kernel_launch(void* const* d_in, const int* in_sizes, int n_in,
                              void* d_out, int out_size, void* d_ws, size_t ws_size,
                              hipStream_t stream) {
    const float* pred   = (const float*)d_in[0];
    const float* target = (const float*)d_in[1];
    float* out = (float*)d_out;
    uint32_t* wsmin = (uint32_t*)d_ws;   // 8 dirb x 8192 x u32 = 256 KiB

    hipMemsetAsync(wsmin, 0xFF, (size_t)8 * NPTS * sizeof(uint32_t), stream);

    dim3 grid(NQG * NCHUNK, 2 * BATCH);   // 256 x 8 = 2048 blocks, 8/CU
    chamfer_partial_kernel<<<grid, THREADS, 0, stream>>>(pred, target, wsmin);
    chamfer_reduce_kernel<<<1, 1024, 0, stream>>>(wsmin, out);
}

// Round 8
// 52.202 us; speedup vs baseline: 1.0461x; 1.0254x over previous
//
#include <hip/hip_runtime.h>
#include <stdint.h>

// Chamfer L1, B=4, N=M=8192, 3-D points.
// u16 fixed-point quantization (4096/unit, +8 offset):
//   pair distance = 2x v_sad_u16 (half-rate: 4 cyc), min via v_min3_u32
//   => 18 cyc / 2 pairs / lane.  VALU floor = 8.39M wave-pairs x 9 cyc
//   / 1024 SIMDs = 30.7 us.
// Prep kernel quantizes all 65536 points ONCE into packed uint2 (ws) and
// inits wsmin — main-kernel prologue is 4 coalesced dwordx2 loads, no quant.
// Geometry: QPL=4, 256-ref chunks, 2048 blocks (8 waves/SIMD).
// Per-chunk mins folded via device-scope atomicMin (256 KB ws), then a
// single-block deterministic reduce writes out.

#define BATCH    4
#define NPTS     8192
#define QSCALE   4096.0f
#define QOFFS    8.0f
#define NCHUNK   32
#define CHUNKPTS (NPTS / NCHUNK)   // 256 refs per block
#define THREADS  256
#define QPL      4                 // queries per lane
#define QPB      (THREADS * QPL)   // 1024 queries per block
#define NQG      (NPTS / QPB)      // 8 query groups
#define NPTS_TOT (2 * BATCH * NPTS)   // 65536 points total

static __device__ __forceinline__ uint32_t sad_u16(uint32_t a, uint32_t b, uint32_t c) {
#if __has_builtin(__builtin_amdgcn_sad_u16)
    return __builtin_amdgcn_sad_u16(a, b, c);
#else
    uint32_t d;
    asm("v_sad_u16 %0, %1, %2, %3" : "=v"(d) : "v"(a), "v"(b), "v"(c));
    return d;
#endif
}

static __device__ __forceinline__ uint32_t min3_u32(uint32_t a, uint32_t b, uint32_t c) {
    uint32_t d;
    asm("v_min3_u32 %0, %1, %2, %3" : "=v"(d) : "v"(a), "v"(b), "v"(c));
    return d;
}

static __device__ __forceinline__ uint32_t quant(float x) {
    float v = (x + QOFFS) * QSCALE;
    v = fminf(fmaxf(v, 0.0f), 65535.0f);
    return (uint32_t)(v + 0.5f);
}

// ws layout: [0, 256K): wsmin (64K u32)
//            [256K, 512K): quantized pred  (32768 uint2)
//            [512K, 768K): quantized target(32768 uint2)

__global__ __launch_bounds__(256) void chamfer_prep_kernel(
    const float* __restrict__ pred, const float* __restrict__ target,
    uint32_t* __restrict__ wsmin, uint2* __restrict__ wsq)
{
    const int tid = blockIdx.x * 256 + threadIdx.x;   // 0..65535
    wsmin[tid] = 0xFFFFFFFFu;
    const float* src = (tid < NPTS_TOT / 2)
                     ? pred + (size_t)tid * 3
                     : target + (size_t)(tid - NPTS_TOT / 2) * 3;
    wsq[tid] = make_uint2(quant(src[0]) | (quant(src[1]) << 16), quant(src[2]));
}

__global__ __launch_bounds__(THREADS, 8) void chamfer_partial_kernel(
    const uint2* __restrict__ wsq, uint32_t* __restrict__ wsmin)
{
    __shared__ __align__(16) uint2 tile[CHUNKPTS];   // 2 KiB

    const int t    = threadIdx.x;
    const int qg   = blockIdx.x >> 5;     // 0..7
    const int c    = blockIdx.x & 31;     // 0..31
    const int dirb = blockIdx.y;          // 0..7
    const int dir  = dirb >> 2;           // 0: pred->target, 1: target->pred
    const int b    = dirb & 3;

    const uint2* qbase = wsq + (size_t)dir * (BATCH * NPTS) + (size_t)b * NPTS;
    const uint2* rbase = wsq + (size_t)(1 - dir) * (BATCH * NPTS) + (size_t)b * NPTS;

    // stage this block's 256-ref chunk (1 pt/thread, already quantized)
    tile[t] = rbase[c * CHUNKPTS + t];

    // my 4 queries (coalesced dwordx2 loads, no quant math)
    uint32_t qxy[QPL], qz[QPL], best[QPL];
    #pragma unroll
    for (int k = 0; k < QPL; ++k) {
        uint2 v = qbase[qg * QPB + k * THREADS + t];
        qxy[k]  = v.x;
        qz[k]   = v.y;
        best[k] = 0xFFFFFFFFu;
    }
    __syncthreads();

    // scan: one broadcast ds_read_b128 = 2 points, shared by 4 queries
    const uint4* tp = reinterpret_cast<const uint4*>(tile);
    #pragma unroll 4
    for (int j = 0; j < CHUNKPTS / 2; ++j) {
        uint4 v = tp[j];
        #pragma unroll
        for (int k = 0; k < QPL; ++k) {
            uint32_t d0 = sad_u16(v.y, qz[k], sad_u16(v.x, qxy[k], 0u));
            uint32_t d1 = sad_u16(v.w, qz[k], sad_u16(v.z, qxy[k], 0u));
            best[k] = min3_u32(d0, d1, best[k]);
        }
    }

    // fold this chunk's per-query mins into the global per-query min
    uint32_t* dst = wsmin + (size_t)dirb * NPTS + qg * QPB + t;
    #pragma unroll
    for (int k = 0; k < QPL; ++k)
        atomicMin(&dst[k * THREADS], best[k]);
}

__global__ __launch_bounds__(1024) void chamfer_reduce_kernel(
    const uint32_t* __restrict__ wsmin, float* __restrict__ out)
{
    __shared__ float ssum[16];
    const int t = threadIdx.x;
    const uint4* p = reinterpret_cast<const uint4*>(wsmin);   // 16384 uint4
    float s = 0.0f;
    #pragma unroll
    for (int i = 0; i < 16; ++i) {
        uint4 v = p[t + i * 1024];
        s += (float)v.x + (float)v.y + (float)v.z + (float)v.w;
    }
    #pragma unroll
    for (int off = 32; off > 0; off >>= 1)
        s += __shfl_down(s, off);
    if ((t & 63) == 0) ssum[t >> 6] = s;
    __syncthreads();
    if (t == 0) {
        float tot = 0.0f;
        #pragma unroll
        for (int w = 0; w < 16; ++w) tot += ssum[w];
        out[0] = tot * (1.0f / (QSCALE * (float)BATCH));
    }
}

extern "C" void kernel_launch(void* const* d_in, const int* in_sizes, int n_in,
                              void* d_out, int out_size, void* d_ws, size_t ws_size,
                              hipStream_t stream) {
    const float* pred   = (const float*)d_in[0];
    const float* target = (const float*)d_in[1];
    float* out = (float*)d_out;
    uint32_t* wsmin = (uint32_t*)d_ws;                       // 256 KiB
    uint2*    wsq   = (uint2*)((char*)d_ws + 256 * 1024);    // 512 KiB

    chamfer_prep_kernel<<<NPTS_TOT / 256, 256, 0, stream>>>(pred, target, wsmin, wsq);

    dim3 grid(NQG * NCHUNK, 2 * BATCH);   // 256 x 8 = 2048 blocks, 8/CU
    chamfer_partial_kernel<<<grid, THREADS, 0, stream>>>(wsq, wsmin);
    chamfer_reduce_kernel<<<1, 1024, 0, stream>>>(wsmin, out);
}

// Round 9
// 39.931 us; speedup vs baseline: 1.3676x; 1.3073x over previous
//
#include <hip/hip_runtime.h>
#include <stdint.h>

// Chamfer L1, B=4, N=M=8192, 3-D points — SYMMETRIC single-pass.
// Each pairwise distance is computed ONCE and updates both the forward
// (pred-query) row-min and backward (target-query) col-min.
// u16 fixed-point quantization (4096/unit, +8 offset):
//   pair distance = 2x v_sad_u16 (4 cyc) + amortized v_min3_u32.
// Structure: wave tile = 128 preds x 512 targets. 4 groups of 16 lanes;
// lane owns NP=8 preds (stationary, row accs) and NT=8 targets
// (rotating with col accs through a 16-lane ring via DPP row_ror:1 —
// pure VALU, zero LDS). 16 rounds/tile. 4096 waves = 4 waves/SIMD,
// fully resident. Floor ~18.4 us.

#define BATCH    4
#define NPTS     8192
#define QSCALE   4096.0f
#define QOFFS    8.0f
#define NP       8
#define NT       8
#define NPTS_TOT (2 * BATCH * NPTS)   // 65536

static __device__ __forceinline__ uint32_t sad_u16(uint32_t a, uint32_t b, uint32_t c) {
#if __has_builtin(__builtin_amdgcn_sad_u16)
    return __builtin_amdgcn_sad_u16(a, b, c);
#else
    uint32_t d;
    asm("v_sad_u16 %0, %1, %2, %3" : "=v"(d) : "v"(a), "v"(b), "v"(c));
    return d;
#endif
}

static __device__ __forceinline__ uint32_t min3_u32(uint32_t a, uint32_t b, uint32_t c) {
    uint32_t d;
    asm("v_min3_u32 %0, %1, %2, %3" : "=v"(d) : "v"(a), "v"(b), "v"(c));
    return d;
}

static __device__ __forceinline__ uint32_t umin32(uint32_t a, uint32_t b) {
    return a < b ? a : b;
}

// rotate within each 16-lane row: lane l receives lane (l+1)&15's value
static __device__ __forceinline__ uint32_t rot16(uint32_t v) {
    return (uint32_t)__builtin_amdgcn_update_dpp(0, (int)v, 0x121, 0xF, 0xF, true);
}

static __device__ __forceinline__ uint32_t quant(float x) {
    float v = (x + QOFFS) * QSCALE;
    v = fminf(fmaxf(v, 0.0f), 65535.0f);
    return (uint32_t)(v + 0.5f);
}

// ws layout: [0, 256K): wsmin (64K u32: [dirb 0..7][8192])
//            [256K, 768K): quantized points (uint2: 32768 pred, 32768 target)

__global__ __launch_bounds__(256) void chamfer_prep_kernel(
    const float* __restrict__ pred, const float* __restrict__ target,
    uint32_t* __restrict__ wsmin, uint2* __restrict__ wsq)
{
    const int tid = blockIdx.x * 256 + threadIdx.x;   // 0..65535
    wsmin[tid] = 0xFFFFFFFFu;
    const float* src = (tid < NPTS_TOT / 2)
                     ? pred + (size_t)tid * 3
                     : target + (size_t)(tid - NPTS_TOT / 2) * 3;
    wsq[tid] = make_uint2(quant(src[0]) | (quant(src[1]) << 16), quant(src[2]));
}

__global__ __launch_bounds__(256, 4) void chamfer_sym_kernel(
    const uint2* __restrict__ wsq, uint32_t* __restrict__ wsmin)
{
    const int t    = threadIdx.x;
    const int wid  = t >> 6;
    const int lane = t & 63;
    const int g16  = lane >> 4;
    const int l16  = lane & 15;

    // global wave-tile id: [0,4096)
    const int tid    = blockIdx.x * 4 + wid;
    const int b      = tid >> 10;          // batch 0..3
    const int rest   = tid & 1023;
    const int pblock = rest >> 4;          // 0..63 (128 preds each)
    const int tblock = rest & 15;          // 0..15 (512 targets each)

    const int pb = pblock * 128;                       // pred base (within batch)
    const int tb = tblock * 512;                       // target base (within batch)
    const uint2* qsrc = wsq + (size_t)b * NPTS;                  // preds of batch b
    const uint2* tsrc = wsq + (size_t)(BATCH + b) * NPTS;        // targets of batch b

    // stationary preds + row accs
    uint32_t qxy[NP], qz[NP], rowacc[NP];
    #pragma unroll
    for (int k = 0; k < NP; ++k) {
        uint2 v = qsrc[pb + k * 16 + l16];
        qxy[k] = v.x;  qz[k] = v.y;  rowacc[k] = 0xFFFFFFFFu;
    }

    // rotating targets + col accs
    uint32_t txy[NT], tz[NT], colacc[NT];
    #pragma unroll
    for (int m = 0; m < NT; ++m) {
        uint2 v = tsrc[tb + g16 * 128 + m * 16 + l16];
        txy[m] = v.x;  tz[m] = v.y;  colacc[m] = 0xFFFFFFFFu;
    }

    // 16-round ring: each round computes NP x NT pairs, updates both accs,
    // then rotates targets+colaccs one step; after 16 rounds data is home.
    #pragma unroll 2
    for (int r = 0; r < 16; ++r) {
        #pragma unroll
        for (int kk = 0; kk < NP; kk += 2) {
            uint32_t d0[NT], d1[NT];
            #pragma unroll
            for (int m = 0; m < NT; ++m) {
                d0[m] = sad_u16(tz[m], qz[kk],     sad_u16(txy[m], qxy[kk],     0u));
                d1[m] = sad_u16(tz[m], qz[kk + 1], sad_u16(txy[m], qxy[kk + 1], 0u));
            }
            rowacc[kk]     = min3_u32(d0[0], d0[1], min3_u32(d0[2], d0[3],
                             min3_u32(d0[4], d0[5], min3_u32(d0[6], d0[7], rowacc[kk]))));
            rowacc[kk + 1] = min3_u32(d1[0], d1[1], min3_u32(d1[2], d1[3],
                             min3_u32(d1[4], d1[5], min3_u32(d1[6], d1[7], rowacc[kk + 1]))));
            #pragma unroll
            for (int m = 0; m < NT; ++m)
                colacc[m] = min3_u32(d0[m], d1[m], colacc[m]);
        }
        #pragma unroll
        for (int m = 0; m < NT; ++m) {
            txy[m]    = rot16(txy[m]);
            tz[m]     = rot16(tz[m]);
            colacc[m] = rot16(colacc[m]);
        }
    }

    // forward (pred as query): reduce the 4 duplicate groups, then atomics
    uint32_t* fmin = wsmin + (size_t)b * NPTS;
    #pragma unroll
    for (int k = 0; k < NP; ++k) {
        uint32_t v = rowacc[k];
        v = umin32(v, (uint32_t)__shfl_xor((int)v, 16));
        v = umin32(v, (uint32_t)__shfl_xor((int)v, 32));
        if (g16 == 0)
            atomicMin(&fmin[pb + k * 16 + l16], v);
    }

    // backward (target as query): groups own distinct targets
    uint32_t* bmin = wsmin + (size_t)(BATCH + b) * NPTS;
    #pragma unroll
    for (int m = 0; m < NT; ++m)
        atomicMin(&bmin[tb + g16 * 128 + m * 16 + l16], colacc[m]);
}

__global__ __launch_bounds__(1024) void chamfer_reduce_kernel(
    const uint32_t* __restrict__ wsmin, float* __restrict__ out)
{
    __shared__ float ssum[16];
    const int t = threadIdx.x;
    const uint4* p = reinterpret_cast<const uint4*>(wsmin);   // 16384 uint4
    float s = 0.0f;
    #pragma unroll
    for (int i = 0; i < 16; ++i) {
        uint4 v = p[t + i * 1024];
        s += (float)v.x + (float)v.y + (float)v.z + (float)v.w;
    }
    #pragma unroll
    for (int off = 32; off > 0; off >>= 1)
        s += __shfl_down(s, off);
    if ((t & 63) == 0) ssum[t >> 6] = s;
    __syncthreads();
    if (t == 0) {
        float tot = 0.0f;
        #pragma unroll
        for (int w = 0; w < 16; ++w) tot += ssum[w];
        out[0] = tot * (1.0f / (QSCALE * (float)BATCH));
    }
}

extern "C" void kernel_launch(void* const* d_in, const int* in_sizes, int n_in,
                              void* d_out, int out_size, void* d_ws, size_t ws_size,
                              hipStream_t stream) {
    const float* pred   = (const float*)d_in[0];
    const float* target = (const float*)d_in[1];
    float* out = (float*)d_out;
    uint32_t* wsmin = (uint32_t*)d_ws;                       // 256 KiB
    uint2*    wsq   = (uint2*)((char*)d_ws + 256 * 1024);    // 512 KiB

    chamfer_prep_kernel<<<NPTS_TOT / 256, 256, 0, stream>>>(pred, target, wsmin, wsq);

    // 4096 wave-tiles, 4 waves/block -> 1024 blocks (4/CU, 4 waves/SIMD)
    chamfer_sym_kernel<<<1024, 256, 0, stream>>>(wsq, wsmin);

    chamfer_reduce_kernel<<<1, 1024, 0, stream>>>(wsmin, out);
}

// Round 10
// 37.844 us; speedup vs baseline: 1.4430x; 1.0552x over previous
//
#include <hip/hip_runtime.h>
#include <stdint.h>

// Chamfer L1, B=4, N=M=8192, 3-D points — SYMMETRIC single-pass.
// Each pairwise distance computed ONCE, updating both the forward (pred)
// row-min and backward (target) col-min.
// u16 fixed-point quantization (4096/unit, +8 offset):
//   pair = 2x v_sad_u16 (4 cyc) + ~2.75 cyc amortized min3 => 10.75 cyc/pair
//   covering BOTH directions. Issue floor ~21 us incl. per-tile overheads.
// Structure: wave tile = 128 preds x 256 targets. 4 groups of 16 lanes;
// lane owns NP=8 preds (stationary rows) and NT=4 targets (rotating cols,
// in-place DPP row_ror:1 — single v_mov_b32_dpp, zero LDS). ~54 VGPR ->
// 8 waves/SIMD (launch_bounds(256,8)), 8192 waves = 2048 blocks, 8/CU.

#define BATCH    4
#define NPTS     8192
#define QSCALE   4096.0f
#define QOFFS    8.0f
#define NP       8
#define NT       4
#define NPTS_TOT (2 * BATCH * NPTS)   // 65536

static __device__ __forceinline__ uint32_t sad_u16(uint32_t a, uint32_t b, uint32_t c) {
#if __has_builtin(__builtin_amdgcn_sad_u16)
    return __builtin_amdgcn_sad_u16(a, b, c);
#else
    uint32_t d;
    asm("v_sad_u16 %0, %1, %2, %3" : "=v"(d) : "v"(a), "v"(b), "v"(c));
    return d;
#endif
}

static __device__ __forceinline__ uint32_t min3_u32(uint32_t a, uint32_t b, uint32_t c) {
    uint32_t d;
    asm("v_min3_u32 %0, %1, %2, %3" : "=v"(d) : "v"(a), "v"(b), "v"(c));
    return d;
}

static __device__ __forceinline__ uint32_t umin32(uint32_t a, uint32_t b) {
    return a < b ? a : b;
}

// in-place rotate within each 16-lane row (dst==src==old: no extra mov)
static __device__ __forceinline__ uint32_t rot16(uint32_t v) {
    return (uint32_t)__builtin_amdgcn_update_dpp((int)v, (int)v, 0x121, 0xF, 0xF, false);
}

static __device__ __forceinline__ uint32_t quant(float x) {
    float v = (x + QOFFS) * QSCALE;
    v = fminf(fmaxf(v, 0.0f), 65535.0f);
    return (uint32_t)(v + 0.5f);
}

// ws layout: [0, 256K): wsmin (64K u32: [dir 0..1][batch 0..3][8192])
//            [256K, 768K): quantized points (uint2: 32768 pred, 32768 target)

__global__ __launch_bounds__(256) void chamfer_prep_kernel(
    const float* __restrict__ pred, const float* __restrict__ target,
    uint32_t* __restrict__ wsmin, uint2* __restrict__ wsq,
    float* __restrict__ out)
{
    const int tid = blockIdx.x * 256 + threadIdx.x;   // 0..65535
    if (tid == 0) out[0] = 0.0f;
    wsmin[tid] = 0xFFFFFFFFu;
    const float* src = (tid < NPTS_TOT / 2)
                     ? pred + (size_t)tid * 3
                     : target + (size_t)(tid - NPTS_TOT / 2) * 3;
    wsq[tid] = make_uint2(quant(src[0]) | (quant(src[1]) << 16), quant(src[2]));
}

__global__ __launch_bounds__(256, 8) void chamfer_sym_kernel(
    const uint2* __restrict__ wsq, uint32_t* __restrict__ wsmin)
{
    const int t    = threadIdx.x;
    const int wid  = t >> 6;
    const int lane = t & 63;
    const int g16  = lane >> 4;
    const int l16  = lane & 15;

    // global wave-tile id: [0, 8192)
    const int tid    = blockIdx.x * 4 + wid;
    const int b      = tid >> 11;          // batch 0..3
    const int rest   = tid & 2047;
    const int pblock = rest >> 5;          // 0..63  (128 preds each)
    const int tblock = rest & 31;          // 0..31  (256 targets each)

    const int pb = pblock * 128;
    const int tb = tblock * 256;
    const uint2* qsrc = wsq + (size_t)b * NPTS;                  // preds of batch b
    const uint2* tsrc = wsq + (size_t)(BATCH + b) * NPTS;        // targets of batch b

    // stationary preds + row accs
    uint32_t qxy[NP], qz[NP], rowacc[NP];
    #pragma unroll
    for (int k = 0; k < NP; ++k) {
        uint2 v = qsrc[pb + k * 16 + l16];
        qxy[k] = v.x;  qz[k] = v.y;  rowacc[k] = 0xFFFFFFFFu;
    }

    // rotating targets + col accs (group owns 64 distinct targets)
    uint32_t txy[NT], tz[NT], colacc[NT];
    #pragma unroll
    for (int m = 0; m < NT; ++m) {
        uint2 v = tsrc[tb + g16 * 64 + m * 16 + l16];
        txy[m] = v.x;  tz[m] = v.y;  colacc[m] = 0xFFFFFFFFu;
    }

    // 16-round ring: NP x NT pairs per round, both accs updated, then
    // targets+colaccs rotate one lane; after 16 rounds data is home.
    #pragma unroll 4
    for (int r = 0; r < 16; ++r) {
        #pragma unroll
        for (int kk = 0; kk < NP; kk += 2) {
            uint32_t d0[NT], d1[NT];
            #pragma unroll
            for (int m = 0; m < NT; ++m) {
                d0[m] = sad_u16(tz[m], qz[kk],     sad_u16(txy[m], qxy[kk],     0u));
                d1[m] = sad_u16(tz[m], qz[kk + 1], sad_u16(txy[m], qxy[kk + 1], 0u));
            }
            rowacc[kk]     = min3_u32(d0[0], d0[1], min3_u32(d0[2], d0[3], rowacc[kk]));
            rowacc[kk + 1] = min3_u32(d1[0], d1[1], min3_u32(d1[2], d1[3], rowacc[kk + 1]));
            #pragma unroll
            for (int m = 0; m < NT; ++m)
                colacc[m] = min3_u32(d0[m], d1[m], colacc[m]);
        }
        #pragma unroll
        for (int m = 0; m < NT; ++m) {
            txy[m]    = rot16(txy[m]);
            tz[m]     = rot16(tz[m]);
            colacc[m] = rot16(colacc[m]);
        }
    }

    // forward (pred as query): min across the 4 duplicate groups, then atomics
    uint32_t* fmin = wsmin + (size_t)b * NPTS;
    #pragma unroll
    for (int k = 0; k < NP; ++k) {
        uint32_t v = rowacc[k];
        v = umin32(v, (uint32_t)__shfl_xor((int)v, 16));
        v = umin32(v, (uint32_t)__shfl_xor((int)v, 32));
        if (g16 == 0)
            atomicMin(&fmin[pb + k * 16 + l16], v);
    }

    // backward (target as query): groups own distinct targets
    uint32_t* bmin = wsmin + (size_t)(BATCH + b) * NPTS;
    #pragma unroll
    for (int m = 0; m < NT; ++m)
        atomicMin(&bmin[tb + g16 * 64 + m * 16 + l16], colacc[m]);
}

__global__ __launch_bounds__(256) void chamfer_reduce_kernel(
    const uint32_t* __restrict__ wsmin, float* __restrict__ out)
{
    const int t = threadIdx.x;
    const uint4* p = reinterpret_cast<const uint4*>(wsmin);   // 16384 uint4
    float s = 0.0f;
    #pragma unroll
    for (int i = 0; i < 4; ++i) {
        uint4 v = p[blockIdx.x * 1024 + i * 256 + t];
        s += (float)v.x + (float)v.y + (float)v.z + (float)v.w;
    }
    #pragma unroll
    for (int off = 32; off > 0; off >>= 1)
        s += __shfl_down(s, off);
    if ((t & 63) == 0)
        atomicAdd(out, s * (1.0f / (QSCALE * (float)BATCH)));
}

extern "C" void kernel_launch(void* const* d_in, const int* in_sizes, int n_in,
                              void* d_out, int out_size, void* d_ws, size_t ws_size,
                              hipStream_t stream) {
    const float* pred   = (const float*)d_in[0];
    const float* target = (const float*)d_in[1];
    float* out = (float*)d_out;
    uint32_t* wsmin = (uint32_t*)d_ws;                       // 256 KiB
    uint2*    wsq   = (uint2*)((char*)d_ws + 256 * 1024);    // 512 KiB

    chamfer_prep_kernel<<<NPTS_TOT / 256, 256, 0, stream>>>(pred, target, wsmin, wsq, out);

    // 8192 wave-tiles, 4 waves/block -> 2048 blocks (8/CU, 8 waves/SIMD)
    chamfer_sym_kernel<<<2048, 256, 0, stream>>>(wsq, wsmin);

    chamfer_reduce_kernel<<<16, 256, 0, stream>>>(wsmin, out);
}